// Round 2
// baseline (4777.492 us; speedup 1.0000x reference)
//
#include <hip/hip_runtime.h>
#include <hip/hip_fp16.h>

// Problem constants
#define B_   64
#define T_   512
#define I_   128
#define H_   256
#define G4_  1024   // 4*H
#define R_   20
#define DA_  50
#define C_   10

typedef _Float16 half2_t __attribute__((ext_vector_type(2)));
typedef _Float16 half8_t __attribute__((ext_vector_type(8)));

union H8 {
  half8_t v8;
  half2_t h2[4];
};

// ---------------------------------------------------------------------------
// K0: pack W_hh [256][1024] fp32 -> Wq[g][k2] half2 (column-major per gate col)
// Wq[g*128 + k2] = (Whh[2*k2][g], Whh[2*k2+1][g])
// ---------------------------------------------------------------------------
__global__ __launch_bounds__(256) void k0_pack(const float* __restrict__ Whh,
                                               half2_t* __restrict__ Wq) {
  int idx = blockIdx.x * 256 + threadIdx.x;   // 0..131071
  int g = idx & 1023, k2 = idx >> 10;         // reads coalesced over g
  half2_t h;
  h.x = (_Float16)Whh[(2 * k2) * G4_ + g];
  h.y = (_Float16)Whh[(2 * k2 + 1) * G4_ + g];
  Wq[g * 128 + k2] = h;
}

// ---------------------------------------------------------------------------
// K_init: zero the per-b sync counters
// ---------------------------------------------------------------------------
__global__ void k_init(int* __restrict__ cnt) {
  cnt[threadIdx.x] = 0;
}

// ---------------------------------------------------------------------------
// K1: S[b][r][t] = (tanh(x[b,t,:]@W1[r,:]+b1)@W2[r,:]) + b2   (layout [B,R,T])
// one wave per (b,t)
// ---------------------------------------------------------------------------
__global__ __launch_bounds__(64) void k1_scores(const float* __restrict__ x,
                                                const float* __restrict__ W1,
                                                const float* __restrict__ b1,
                                                const float* __restrict__ W2,
                                                const float* __restrict__ b2,
                                                float* __restrict__ S) {
  int bt = blockIdx.x;            // b*512 + t
  int b = bt >> 9, t = bt & 511;
  int l = threadIdx.x;
  __shared__ float xs[I_];
  __shared__ float as[DA_];
  const float* xr = x + (size_t)bt * I_;
  xs[l] = xr[l];
  xs[l + 64] = xr[l + 64];
  __syncthreads();
  if (l < DA_) {
    float acc = b1[l];
    const float* wr = W1 + l * I_;
#pragma unroll 8
    for (int k = 0; k < I_; k++) acc += xs[k] * wr[k];
    as[l] = tanhf(acc);
  }
  __syncthreads();
  if (l < R_) {
    float acc = b2[l];
    const float* wr = W2 + l * DA_;
#pragma unroll 5
    for (int d = 0; d < DA_; d++) acc += as[d] * wr[d];
    S[((size_t)(b * R_ + l)) * T_ + t] = acc;
  }
}

// ---------------------------------------------------------------------------
// K2: per (b,r): m = max_t S; E = exp(S-m); invd[t] = 1/cumsum(E)[t]
// ---------------------------------------------------------------------------
__global__ __launch_bounds__(64) void k2_prefix(const float* __restrict__ S,
                                                float* __restrict__ E,
                                                float* __restrict__ invd) {
  int br = blockIdx.x;            // b*20 + r
  int l = threadIdx.x;
  const float* Sr = S + (size_t)br * T_;
  float v[8];
  float m = -1e30f;
#pragma unroll
  for (int c = 0; c < 8; c++) {
    v[c] = Sr[c * 64 + l];
    m = fmaxf(m, v[c]);
  }
#pragma unroll
  for (int off = 32; off; off >>= 1) m = fmaxf(m, __shfl_xor(m, off));
  float carry = 0.f;
  for (int c = 0; c < 8; c++) {
    float e = expf(v[c] - m);
    float s = e;
#pragma unroll
    for (int off = 1; off < 64; off <<= 1) {
      float u = __shfl_up(s, off);
      if (l >= off) s += u;
    }
    E[(size_t)br * T_ + c * 64 + l] = e;
    invd[(size_t)br * T_ + c * 64 + l] = 1.f / (carry + s);
    carry += __shfl(s, 63);
  }
}

// ---------------------------------------------------------------------------
// K3: M[b,t,i] = (1/R) * sum_r (sum_{s<=t} E[b,s,r] x[b,s,i]) * invd[b,t,r]
// ---------------------------------------------------------------------------
__global__ __launch_bounds__(128) void k3_context(const float* __restrict__ x,
                                                  const float* __restrict__ E,
                                                  const float* __restrict__ invd,
                                                  float* __restrict__ M) {
  int b = blockIdx.x;
  int i = threadIdx.x;
  __shared__ float es[2][R_], ds[2][R_];
  float acc[R_];
#pragma unroll
  for (int r = 0; r < R_; r++) acc[r] = 0.f;
  float rE = 0.f, rD = 0.f;
  if (i < R_)
    rE = E[((size_t)(b * R_ + i)) * T_ + 0];
  else if (i < 2 * R_)
    rD = invd[((size_t)(b * R_ + (i - R_))) * T_ + 0];
  const float* xb = x + (size_t)b * T_ * I_;
  float xv = xb[i];
  int buf = 0;
  for (int t = 0; t < T_; t++) {
    if (i < R_) es[buf][i] = rE;
    else if (i < 2 * R_) ds[buf][i - R_] = rD;
    __syncthreads();
    if (t + 1 < T_) {
      if (i < R_)
        rE = E[((size_t)(b * R_ + i)) * T_ + t + 1];
      else if (i < 2 * R_)
        rD = invd[((size_t)(b * R_ + (i - R_))) * T_ + t + 1];
    }
    float xcur = xv;
    if (t + 1 < T_) xv = xb[(size_t)(t + 1) * I_ + i];
    float s = 0.f;
#pragma unroll
    for (int r = 0; r < R_; r++) {
      acc[r] += es[buf][r] * xcur;
      s += acc[r] * ds[buf][r];
    }
    M[(size_t)b * T_ * I_ + (size_t)t * I_ + i] = s * (1.0f / R_);
    buf ^= 1;
  }
}

// ---------------------------------------------------------------------------
// K4: gx[row][g] = M[row,:] @ W_ih[:,g] + b[g].  Output fp16.
// ---------------------------------------------------------------------------
__global__ __launch_bounds__(256) void k4_gemm(const float* __restrict__ Mm,
                                               const float* __restrict__ Wih,
                                               const float* __restrict__ bg,
                                               __half* __restrict__ gx) {
  __shared__ float As[I_][64];   // [k][row]
  __shared__ float Bs[I_][64];   // [k][col]
  int row0 = blockIdx.x * 64, col0 = blockIdx.y * 64;
  int tid = threadIdx.x;
#pragma unroll
  for (int ch = 0; ch < 8; ch++) {
    int fidx = ch * 256 + tid;
    int r = fidx >> 5;
    int kk = (fidx & 31) << 2;
    float4 f = ((const float4*)(Mm + (size_t)(row0 + r) * I_))[fidx & 31];
    As[kk + 0][r] = f.x;
    As[kk + 1][r] = f.y;
    As[kk + 2][r] = f.z;
    As[kk + 3][r] = f.w;
  }
#pragma unroll
  for (int ch = 0; ch < 8; ch++) {
    int fidx = ch * 256 + tid;
    int k = fidx >> 4;
    int c4 = (fidx & 15) << 2;
    float4 f = *((const float4*)(Wih + (size_t)k * G4_ + col0 + c4));
    *((float4*)&Bs[k][c4]) = f;
  }
  __syncthreads();
  int ty = tid >> 4, tx = tid & 15;
  float acc[4][4] = {};
#pragma unroll 4
  for (int k = 0; k < I_; k++) {
    float4 a = *((float4*)&As[k][ty << 2]);
    float4 bq = *((float4*)&Bs[k][tx << 2]);
    acc[0][0] += a.x * bq.x; acc[0][1] += a.x * bq.y; acc[0][2] += a.x * bq.z; acc[0][3] += a.x * bq.w;
    acc[1][0] += a.y * bq.x; acc[1][1] += a.y * bq.y; acc[1][2] += a.y * bq.z; acc[1][3] += a.y * bq.w;
    acc[2][0] += a.z * bq.x; acc[2][1] += a.z * bq.y; acc[2][2] += a.z * bq.z; acc[2][3] += a.z * bq.w;
    acc[3][0] += a.w * bq.x; acc[3][1] += a.w * bq.y; acc[3][2] += a.w * bq.z; acc[3][3] += a.w * bq.w;
  }
#pragma unroll
  for (int ii = 0; ii < 4; ii++) {
#pragma unroll
    for (int jj = 0; jj < 4; jj++) {
      int row = row0 + (ty << 2) + ii;
      int col = col0 + (tx << 2) + jj;
      gx[(size_t)row * G4_ + col] = __float2half(acc[ii][jj] + bg[col]);
    }
  }
}

// ---------------------------------------------------------------------------
// K5: LSTM scan, 4 blocks per batch element, W_hh register-resident (fp16).
// grid = part*64 + b (siblings share XCD under round-robin dispatch).
// Block: 512 threads. col c = tid>>1 in [0,256), k-half kh = tid&1.
// gate = c>>6, uloc = c&63, gcol = gate*256 + p*64 + uloc.
// Per-step h exchange via double-buffered fp16 Hg[2][B][256] + cnt[b] flag.
// ---------------------------------------------------------------------------
__global__ __launch_bounds__(512, 2) void k5_lstm(const __half* __restrict__ gx,
                                                  const half2_t* __restrict__ Wq,
                                                  __half* __restrict__ Hg,
                                                  int* __restrict__ cnt,
                                                  float* __restrict__ hT) {
  int b = blockIdx.x & 63;
  int p = blockIdx.x >> 6;
  int tid = threadIdx.x;
  int kh = tid & 1;
  int c = tid >> 1;
  int gate = c >> 6, uloc = c & 63;
  int gcol = gate * 256 + p * 64 + uloc;

  __shared__ __align__(16) half2_t hs[H_ / 2];   // staged h (256 fp16)
  __shared__ float gsum[256];

  // Load W slice into registers: 64 half2 (= 64 VGPRs) per thread.
  H8 w[16];
  const H8* wp = (const H8*)(Wq + (size_t)gcol * 128 + kh * 64);
#pragma unroll
  for (int i = 0; i < 16; i++) w[i] = wp[i];

  float cstate = 1.0f;            // c0 = 1 (owned by tid < 64)
  const __half* gxb = gx + (size_t)b * T_ * G4_;

  for (int t = 0; t < T_; t++) {
    // ---- stage h into LDS ----
    if (t == 0) {
      if (tid < 128) {
        half2_t o;
        o.x = (_Float16)1.0f;
        o.y = (_Float16)1.0f;
        hs[tid] = o;               // h0 = 1
      }
    } else {
      if (tid == 0) {
        while (__hip_atomic_load(&cnt[b], __ATOMIC_ACQUIRE,
                                 __HIP_MEMORY_SCOPE_AGENT) < 4 * t) {}
      }
      __syncthreads();
      if (tid < 128) {
        const unsigned* src =
            (const unsigned*)(Hg + (size_t)(t & 1) * B_ * H_ + b * H_);
        unsigned v = __hip_atomic_load(src + tid, __ATOMIC_RELAXED,
                                       __HIP_MEMORY_SCOPE_AGENT);
        ((unsigned*)hs)[tid] = v;
      }
    }
    __syncthreads();

    // ---- gate partial dot: s over k in [kh*128, kh*128+128) ----
    float s = (float)gxb[(size_t)t * G4_ + gcol];
    if (kh) s = 0.f;
#pragma unroll
    for (int i = 0; i < 16; i++) {
      H8 hv;
      hv.v8 = *(const half8_t*)(hs + kh * 64 + i * 4);
      s = __builtin_amdgcn_fdot2(w[i].h2[0], hv.h2[0], s, false);
      s = __builtin_amdgcn_fdot2(w[i].h2[1], hv.h2[1], s, false);
      s = __builtin_amdgcn_fdot2(w[i].h2[2], hv.h2[2], s, false);
      s = __builtin_amdgcn_fdot2(w[i].h2[3], hv.h2[3], s, false);
    }
    s += __shfl_xor(s, 1);
    if (kh == 0) gsum[c] = s;
    __syncthreads();

    // ---- cell update: tid < 64 owns unit p*64+tid ----
    if (tid < 64) {
      float vi = gsum[tid], vf = gsum[64 + tid], vg = gsum[128 + tid],
            vo = gsum[192 + tid];
      vi = 1.f / (1.f + expf(-vi));
      vf = 1.f / (1.f + expf(-vf));
      vo = 1.f / (1.f + expf(-vo));
      vg = tanhf(vg);
      cstate = vf * cstate + vi * vg;
      float h = vo * tanhf(cstate);
      unsigned short hb = __half_as_ushort(__float2half(h));
      unsigned short* dst = (unsigned short*)(Hg +
          (size_t)((t + 1) & 1) * B_ * H_ + b * H_ + p * 64 + tid);
      __hip_atomic_store(dst, hb, __ATOMIC_RELAXED, __HIP_MEMORY_SCOPE_AGENT);
      if (t == T_ - 1) hT[b * H_ + p * 64 + tid] = h;
    }
    __syncthreads();   // vmcnt(0) drain: h stores agent-visible

    if (tid == 0)
      __hip_atomic_fetch_add(&cnt[b], 1, __ATOMIC_RELEASE,
                             __HIP_MEMORY_SCOPE_AGENT);
  }
}

// ---------------------------------------------------------------------------
// K6: logits = hT @ Wfc^T + bfc; softmax.  One wave per b.
// ---------------------------------------------------------------------------
__global__ __launch_bounds__(64) void k6_head(const float* __restrict__ hT,
                                              const float* __restrict__ Wfc,
                                              const float* __restrict__ bfc,
                                              float* __restrict__ out) {
  int b = blockIdx.x, l = threadIdx.x;
  const float* h = hT + b * H_;
  float p[C_];
#pragma unroll
  for (int c = 0; c < C_; c++) p[c] = 0.f;
#pragma unroll
  for (int q = 0; q < 4; q++) {
    float hv = h[q * 64 + l];
#pragma unroll
    for (int c = 0; c < C_; c++) p[c] += hv * Wfc[c * H_ + q * 64 + l];
  }
#pragma unroll
  for (int c = 0; c < C_; c++)
    for (int off = 32; off; off >>= 1) p[c] += __shfl_xor(p[c], off);
  if (l == 0) {
    float m = -1e30f, e[C_], sum = 0.f;
    for (int c = 0; c < C_; c++) { p[c] += bfc[c]; m = fmaxf(m, p[c]); }
    for (int c = 0; c < C_; c++) { e[c] = expf(p[c] - m); sum += e[c]; }
    for (int c = 0; c < C_; c++) out[b * C_ + c] = e[c] / sum;
  }
}

// ---------------------------------------------------------------------------
// Workspace layout (float offsets):
//   Hg    [2][B][256] fp16  = dwords [0, 16384)        (aliases S region)
//   cnt   [64] int          = dwords [16384, 16448)    (aliases S region)
//   S     [B,R,T]        wsf + 0        (Hg/cnt only used by k5, after k2)
//   E     [B,R,T]        wsf + 655360
//   INVD  [B,R,T]        wsf + 1310720
//   M     [B,T,I]        wsf + 1966080
//   hT    [B,H]          wsf + 6160384
//   Wq    [1024][128]h2  wsf + 6176768  (131072 dwords)
//   gx    [B,T,4H] fp16  wsf + 6307840  (16777216 dwords)
// ---------------------------------------------------------------------------
extern "C" void kernel_launch(void* const* d_in, const int* in_sizes, int n_in,
                              void* d_out, int out_size, void* d_ws, size_t ws_size,
                              hipStream_t stream) {
  const float* x   = (const float*)d_in[0];
  const float* Wih = (const float*)d_in[1];
  const float* Whh = (const float*)d_in[2];
  const float* bg  = (const float*)d_in[3];
  const float* W1  = (const float*)d_in[4];
  const float* b1  = (const float*)d_in[5];
  const float* W2  = (const float*)d_in[6];
  const float* b2  = (const float*)d_in[7];
  const float* Wfc = (const float*)d_in[8];
  const float* bfc = (const float*)d_in[9];
  float* out = (float*)d_out;

  float* wsf = (float*)d_ws;
  __half* Hg  = (__half*)wsf;              // 2*64*256 fp16 = 16384 dwords
  int*   cnt  = (int*)(wsf + 16384);       // 64 ints
  float* S    = wsf;                       // S aliases Hg/cnt: S dead after k2
  float* E    = wsf + 655360;
  float* INVD = wsf + 1310720;
  float* Mm   = wsf + 1966080;
  float* hT   = wsf + 6160384;
  half2_t* Wq = (half2_t*)(wsf + 6176768);
  __half* gx  = (__half*)(wsf + 6307840);

  hipLaunchKernelGGL(k0_pack,   dim3(512),      dim3(256), 0, stream, Whh, Wq);
  hipLaunchKernelGGL(k1_scores, dim3(B_ * T_),  dim3(64),  0, stream, x, W1, b1, W2, b2, S);
  hipLaunchKernelGGL(k2_prefix, dim3(B_ * R_),  dim3(64),  0, stream, S, E, INVD);
  hipLaunchKernelGGL(k3_context,dim3(B_),       dim3(128), 0, stream, x, E, INVD, Mm);
  hipLaunchKernelGGL(k4_gemm,   dim3(512, 16),  dim3(256), 0, stream, Mm, Wih, bg, gx);
  hipLaunchKernelGGL(k_init,    dim3(1),        dim3(64),  0, stream, cnt);
  hipLaunchKernelGGL(k5_lstm,   dim3(256),      dim3(512), 0, stream, gx, Wq, Hg, cnt, hT);
  hipLaunchKernelGGL(k6_head,   dim3(B_),       dim3(64),  0, stream, hT, Wfc, bfc, out);
}

// Round 3
// 1407.271 us; speedup vs baseline: 3.3949x; 3.3949x over previous
//
#include <hip/hip_runtime.h>
#include <hip/hip_fp16.h>

// Problem constants
#define B_   64
#define T_   512
#define I_   128
#define H_   256
#define G4_  1024   // 4*H
#define R_   20
#define DA_  50
#define C_   10

typedef _Float16 half2_t __attribute__((ext_vector_type(2)));
typedef _Float16 half8_t __attribute__((ext_vector_type(8)));

union H8 {
  half8_t v8;
  half2_t h2[4];
};

__device__ __forceinline__ float fsigmoid(float x) {
  return __fdividef(1.0f, 1.0f + __expf(-x));
}
__device__ __forceinline__ float ftanh(float x) {
  // tanh(x) = 1 - 2/(e^{2x}+1); handles large |x| via inf
  return 1.0f - __fdividef(2.0f, __expf(2.0f * x) + 1.0f);
}

// ---------------------------------------------------------------------------
// K0: pack W_hh [256][1024] fp32 -> Wq[g][k2] half2 (column-major per gate col)
// Wq[g*128 + k2] = (Whh[2*k2][g], Whh[2*k2+1][g])
// ---------------------------------------------------------------------------
__global__ __launch_bounds__(256) void k0_pack(const float* __restrict__ Whh,
                                               half2_t* __restrict__ Wq) {
  int idx = blockIdx.x * 256 + threadIdx.x;   // 0..131071
  int g = idx & 1023, k2 = idx >> 10;         // reads coalesced over g
  half2_t h;
  h.x = (_Float16)Whh[(2 * k2) * G4_ + g];
  h.y = (_Float16)Whh[(2 * k2 + 1) * G4_ + g];
  Wq[g * 128 + k2] = h;
}

// ---------------------------------------------------------------------------
// K_init: zero the h-exchange mailboxes (tags must start != any step index)
// ---------------------------------------------------------------------------
__global__ __launch_bounds__(256) void k_init(unsigned long long* __restrict__ Hx) {
  int i = blockIdx.x * 256 + threadIdx.x;   // 16384 slots
  Hx[i] = 0ull;
}

// ---------------------------------------------------------------------------
// K1: S[b][r][t] = (tanh(x[b,t,:]@W1[r,:]+b1)@W2[r,:]) + b2   (layout [B,R,T])
// ---------------------------------------------------------------------------
__global__ __launch_bounds__(64) void k1_scores(const float* __restrict__ x,
                                                const float* __restrict__ W1,
                                                const float* __restrict__ b1,
                                                const float* __restrict__ W2,
                                                const float* __restrict__ b2,
                                                float* __restrict__ S) {
  int bt = blockIdx.x;            // b*512 + t
  int b = bt >> 9, t = bt & 511;
  int l = threadIdx.x;
  __shared__ float xs[I_];
  __shared__ float as[DA_];
  const float* xr = x + (size_t)bt * I_;
  xs[l] = xr[l];
  xs[l + 64] = xr[l + 64];
  __syncthreads();
  if (l < DA_) {
    float acc = b1[l];
    const float* wr = W1 + l * I_;
#pragma unroll 8
    for (int k = 0; k < I_; k++) acc += xs[k] * wr[k];
    as[l] = tanhf(acc);
  }
  __syncthreads();
  if (l < R_) {
    float acc = b2[l];
    const float* wr = W2 + l * DA_;
#pragma unroll 5
    for (int d = 0; d < DA_; d++) acc += as[d] * wr[d];
    S[((size_t)(b * R_ + l)) * T_ + t] = acc;
  }
}

// ---------------------------------------------------------------------------
// K2: per (b,r): m = max_t S; E = exp(S-m); invd[t] = 1/cumsum(E)[t]
// ---------------------------------------------------------------------------
__global__ __launch_bounds__(64) void k2_prefix(const float* __restrict__ S,
                                                float* __restrict__ E,
                                                float* __restrict__ invd) {
  int br = blockIdx.x;            // b*20 + r
  int l = threadIdx.x;
  const float* Sr = S + (size_t)br * T_;
  float v[8];
  float m = -1e30f;
#pragma unroll
  for (int c = 0; c < 8; c++) {
    v[c] = Sr[c * 64 + l];
    m = fmaxf(m, v[c]);
  }
#pragma unroll
  for (int off = 32; off; off >>= 1) m = fmaxf(m, __shfl_xor(m, off));
  float carry = 0.f;
  for (int c = 0; c < 8; c++) {
    float e = expf(v[c] - m);
    float s = e;
#pragma unroll
    for (int off = 1; off < 64; off <<= 1) {
      float u = __shfl_up(s, off);
      if (l >= off) s += u;
    }
    E[(size_t)br * T_ + c * 64 + l] = e;
    invd[(size_t)br * T_ + c * 64 + l] = 1.f / (carry + s);
    carry += __shfl(s, 63);
  }
}

// ---------------------------------------------------------------------------
// K3: M[b,t,i] = (1/R) * sum_r (sum_{s<=t} E[b,s,r] x[b,s,i]) * invd[b,t,r]
// ---------------------------------------------------------------------------
__global__ __launch_bounds__(128) void k3_context(const float* __restrict__ x,
                                                  const float* __restrict__ E,
                                                  const float* __restrict__ invd,
                                                  float* __restrict__ M) {
  int b = blockIdx.x;
  int i = threadIdx.x;
  __shared__ float es[2][R_], ds[2][R_];
  float acc[R_];
#pragma unroll
  for (int r = 0; r < R_; r++) acc[r] = 0.f;
  float rE = 0.f, rD = 0.f;
  if (i < R_)
    rE = E[((size_t)(b * R_ + i)) * T_ + 0];
  else if (i < 2 * R_)
    rD = invd[((size_t)(b * R_ + (i - R_))) * T_ + 0];
  const float* xb = x + (size_t)b * T_ * I_;
  float xv = xb[i];
  int buf = 0;
  for (int t = 0; t < T_; t++) {
    if (i < R_) es[buf][i] = rE;
    else if (i < 2 * R_) ds[buf][i - R_] = rD;
    __syncthreads();
    if (t + 1 < T_) {
      if (i < R_)
        rE = E[((size_t)(b * R_ + i)) * T_ + t + 1];
      else if (i < 2 * R_)
        rD = invd[((size_t)(b * R_ + (i - R_))) * T_ + t + 1];
    }
    float xcur = xv;
    if (t + 1 < T_) xv = xb[(size_t)(t + 1) * I_ + i];
    float s = 0.f;
#pragma unroll
    for (int r = 0; r < R_; r++) {
      acc[r] += es[buf][r] * xcur;
      s += acc[r] * ds[buf][r];
    }
    M[(size_t)b * T_ * I_ + (size_t)t * I_ + i] = s * (1.0f / R_);
    buf ^= 1;
  }
}

// ---------------------------------------------------------------------------
// K4: gx[row][g] = M[row,:] @ W_ih[:,g] + b[g].  Output fp16.
// ---------------------------------------------------------------------------
__global__ __launch_bounds__(256) void k4_gemm(const float* __restrict__ Mm,
                                               const float* __restrict__ Wih,
                                               const float* __restrict__ bg,
                                               __half* __restrict__ gx) {
  __shared__ float As[I_][64];   // [k][row]
  __shared__ float Bs[I_][64];   // [k][col]
  int row0 = blockIdx.x * 64, col0 = blockIdx.y * 64;
  int tid = threadIdx.x;
#pragma unroll
  for (int ch = 0; ch < 8; ch++) {
    int fidx = ch * 256 + tid;
    int r = fidx >> 5;
    int kk = (fidx & 31) << 2;
    float4 f = ((const float4*)(Mm + (size_t)(row0 + r) * I_))[fidx & 31];
    As[kk + 0][r] = f.x;
    As[kk + 1][r] = f.y;
    As[kk + 2][r] = f.z;
    As[kk + 3][r] = f.w;
  }
#pragma unroll
  for (int ch = 0; ch < 8; ch++) {
    int fidx = ch * 256 + tid;
    int k = fidx >> 4;
    int c4 = (fidx & 15) << 2;
    float4 f = *((const float4*)(Wih + (size_t)k * G4_ + col0 + c4));
    *((float4*)&Bs[k][c4]) = f;
  }
  __syncthreads();
  int ty = tid >> 4, tx = tid & 15;
  float acc[4][4] = {};
#pragma unroll 4
  for (int k = 0; k < I_; k++) {
    float4 a = *((float4*)&As[k][ty << 2]);
    float4 bq = *((float4*)&Bs[k][tx << 2]);
    acc[0][0] += a.x * bq.x; acc[0][1] += a.x * bq.y; acc[0][2] += a.x * bq.z; acc[0][3] += a.x * bq.w;
    acc[1][0] += a.y * bq.x; acc[1][1] += a.y * bq.y; acc[1][2] += a.y * bq.z; acc[1][3] += a.y * bq.w;
    acc[2][0] += a.z * bq.x; acc[2][1] += a.z * bq.y; acc[2][2] += a.z * bq.z; acc[2][3] += a.z * bq.w;
    acc[3][0] += a.w * bq.x; acc[3][1] += a.w * bq.y; acc[3][2] += a.w * bq.z; acc[3][3] += a.w * bq.w;
  }
#pragma unroll
  for (int ii = 0; ii < 4; ii++) {
#pragma unroll
    for (int jj = 0; jj < 4; jj++) {
      int row = row0 + (ty << 2) + ii;
      int col = col0 + (tx << 2) + jj;
      gx[(size_t)row * G4_ + col] = __float2half(acc[ii][jj] + bg[col]);
    }
  }
}

// ---------------------------------------------------------------------------
// K5: LSTM scan, 4 blocks per batch element, W_hh register-resident fp16
// (pinned via asm barrier). Cross-block h exchange is FENCE-FREE: each 8-byte
// mailbox slot = {2 x fp16 h | step tag} written/read as single relaxed
// agent-scope atomics — no acquire/release, no cache invalidates.
// Mailbox Hx[parity][b][4 part][32 slots], double-buffered by step parity.
// Block: 512 threads. col c = tid>>1, k-half kh = tid&1.
// gcol = gate*256 + p*64 + (c&63), gate = c>>6.
// ---------------------------------------------------------------------------
__global__ __launch_bounds__(512, 2) void k5_lstm(
    const __half* __restrict__ gx, const half2_t* __restrict__ Wq,
    unsigned long long* __restrict__ Hx, float* __restrict__ hT) {
  int b = blockIdx.x & 63;
  int p = blockIdx.x >> 6;
  int tid = threadIdx.x;
  int kh = tid & 1;
  int c = tid >> 1;
  int gate = c >> 6, uloc = c & 63;
  int gcol = gate * 256 + p * 64 + uloc;

  __shared__ __align__(16) half2_t hs[H_ / 2];   // staged h (256 fp16)
  __shared__ float gsum[256];

  // Poller role: tid<96 polls remote partition q, slot d.
  int qi = tid >> 5;                 // 0..2 (for tid < 96)
  int q = qi + (qi >= p ? 1 : 0);    // skip own partition
  int d = tid & 31;

  // Load W slice into registers: 64 half2 (= 64 VGPRs) per thread, then pin.
  H8 w[16];
  {
    const H8* wp = (const H8*)(Wq + (size_t)gcol * 128 + kh * 64);
#pragma unroll
    for (int i = 0; i < 16; i++) w[i].v8 = wp[i].v8;
  }
  asm volatile("" ::: "memory");   // compiler barrier: w[] must stay in VGPRs

  float cstate = 1.0f;             // c0 = 1 (owned by tid < 64)
  const __half* gxb = gx + (size_t)b * T_ * G4_;

  for (int t = 0; t < T_; t++) {
    // issue gx load early; consumed after the dot (overlaps poll latency)
    float gxv = 0.f;
    if (!kh) gxv = (float)gxb[(size_t)t * G4_ + gcol];

    // ---- stage h(t) into LDS ----
    if (t == 0) {
      if (tid < 128) {
        half2_t o;
        o.x = (_Float16)1.0f;
        o.y = (_Float16)1.0f;
        hs[tid] = o;               // h0 = 1
      }
    } else if (tid < 96) {
      const unsigned long long* src =
          Hx + ((size_t)(t & 1) * 64 + b) * 128 + q * 32 + d;
      unsigned long long v;
      do {
        v = __hip_atomic_load(src, __ATOMIC_RELAXED, __HIP_MEMORY_SCOPE_AGENT);
      } while ((unsigned)(v >> 32) != (unsigned)t);
      ((unsigned*)hs)[q * 32 + d] = (unsigned)v;
    }
    __syncthreads();

    // ---- partial dot over k-half kh: 64 half2, 4 accumulators ----
    float a0 = 0.f, a1 = 0.f, a2 = 0.f, a3 = 0.f;
#pragma unroll
    for (int i = 0; i < 16; i++) {
      H8 hv;
      hv.v8 = *(const half8_t*)(hs + kh * 64 + i * 4);
      a0 = __builtin_amdgcn_fdot2(w[i].h2[0], hv.h2[0], a0, false);
      a1 = __builtin_amdgcn_fdot2(w[i].h2[1], hv.h2[1], a1, false);
      a2 = __builtin_amdgcn_fdot2(w[i].h2[2], hv.h2[2], a2, false);
      a3 = __builtin_amdgcn_fdot2(w[i].h2[3], hv.h2[3], a3, false);
    }
    float s = (a0 + a1) + (a2 + a3);
    s += __shfl_xor(s, 1);
    if (!kh) gsum[c] = s + gxv;
    __syncthreads();

    // ---- cell update: tid < 64 owns unit p*64+tid (wave 0) ----
    if (tid < 64) {
      float vi = gsum[tid], vf = gsum[64 + tid], vg = gsum[128 + tid],
            vo = gsum[192 + tid];
      vi = fsigmoid(vi);
      vf = fsigmoid(vf);
      vo = fsigmoid(vo);
      vg = ftanh(vg);
      cstate = vf * cstate + vi * vg;
      float h = vo * ftanh(cstate);
      unsigned hu = (unsigned)__half_as_ushort(__float2half(h));
      // own slot for next step's local staging
      ((unsigned short*)hs)[p * 64 + tid] = (unsigned short)hu;
      // pack pair via wave shuffle, even lanes store {h2, tag=t+1}
      unsigned hup = (unsigned)__shfl_xor((int)hu, 1);
      if (!(tid & 1) && (t + 1 < T_)) {
        unsigned long long pkt =
            (unsigned long long)(hu | (hup << 16)) |
            ((unsigned long long)(unsigned)(t + 1) << 32);
        unsigned long long* dst =
            Hx + ((size_t)((t + 1) & 1) * 64 + b) * 128 + p * 32 + (tid >> 1);
        __hip_atomic_store(dst, pkt, __ATOMIC_RELAXED,
                           __HIP_MEMORY_SCOPE_AGENT);
      }
      if (t == T_ - 1) hT[b * H_ + p * 64 + tid] = h;
    }
    // no barrier here: next-iter staging writes disjoint LDS slots, and the
    // staging __syncthreads orders them against all readers.
  }
}

// ---------------------------------------------------------------------------
// K6: logits = hT @ Wfc^T + bfc; softmax.  One wave per b.
// ---------------------------------------------------------------------------
__global__ __launch_bounds__(64) void k6_head(const float* __restrict__ hT,
                                              const float* __restrict__ Wfc,
                                              const float* __restrict__ bfc,
                                              float* __restrict__ out) {
  int b = blockIdx.x, l = threadIdx.x;
  const float* h = hT + b * H_;
  float p[C_];
#pragma unroll
  for (int c = 0; c < C_; c++) p[c] = 0.f;
#pragma unroll
  for (int q = 0; q < 4; q++) {
    float hv = h[q * 64 + l];
#pragma unroll
    for (int c = 0; c < C_; c++) p[c] += hv * Wfc[c * H_ + q * 64 + l];
  }
#pragma unroll
  for (int c = 0; c < C_; c++)
    for (int off = 32; off; off >>= 1) p[c] += __shfl_xor(p[c], off);
  if (l == 0) {
    float m = -1e30f, e[C_], sum = 0.f;
    for (int c = 0; c < C_; c++) { p[c] += bfc[c]; m = fmaxf(m, p[c]); }
    for (int c = 0; c < C_; c++) { e[c] = expf(p[c] - m); sum += e[c]; }
    for (int c = 0; c < C_; c++) out[b * C_ + c] = e[c] / sum;
  }
}

// ---------------------------------------------------------------------------
// Workspace layout (float offsets):
//   Hx    [2][64][128] u64 = dwords [0, 32768)   (aliases S; S dead after k2)
//   S     [B,R,T]        wsf + 0
//   E     [B,R,T]        wsf + 655360
//   INVD  [B,R,T]        wsf + 1310720
//   M     [B,T,I]        wsf + 1966080
//   hT    [B,H]          wsf + 6160384
//   Wq    [1024][128]h2  wsf + 6176768  (131072 dwords)
//   gx    [B,T,4H] fp16  wsf + 6307840  (16777216 dwords)
// ---------------------------------------------------------------------------
extern "C" void kernel_launch(void* const* d_in, const int* in_sizes, int n_in,
                              void* d_out, int out_size, void* d_ws, size_t ws_size,
                              hipStream_t stream) {
  const float* x   = (const float*)d_in[0];
  const float* Wih = (const float*)d_in[1];
  const float* Whh = (const float*)d_in[2];
  const float* bg  = (const float*)d_in[3];
  const float* W1  = (const float*)d_in[4];
  const float* b1  = (const float*)d_in[5];
  const float* W2  = (const float*)d_in[6];
  const float* b2  = (const float*)d_in[7];
  const float* Wfc = (const float*)d_in[8];
  const float* bfc = (const float*)d_in[9];
  float* out = (float*)d_out;

  float* wsf = (float*)d_ws;
  unsigned long long* Hx = (unsigned long long*)wsf;  // 16384 u64 = 128 KB
  float* S    = wsf;                       // S aliases Hx: S dead after k2
  float* E    = wsf + 655360;
  float* INVD = wsf + 1310720;
  float* Mm   = wsf + 1966080;
  float* hT   = wsf + 6160384;
  half2_t* Wq = (half2_t*)(wsf + 6176768);
  __half* gx  = (__half*)(wsf + 6307840);

  hipLaunchKernelGGL(k0_pack,   dim3(512),      dim3(256), 0, stream, Whh, Wq);
  hipLaunchKernelGGL(k1_scores, dim3(B_ * T_),  dim3(64),  0, stream, x, W1, b1, W2, b2, S);
  hipLaunchKernelGGL(k2_prefix, dim3(B_ * R_),  dim3(64),  0, stream, S, E, INVD);
  hipLaunchKernelGGL(k3_context,dim3(B_),       dim3(128), 0, stream, x, E, INVD, Mm);
  hipLaunchKernelGGL(k4_gemm,   dim3(512, 16),  dim3(256), 0, stream, Mm, Wih, bg, gx);
  hipLaunchKernelGGL(k_init,    dim3(64),       dim3(256), 0, stream, Hx);
  hipLaunchKernelGGL(k5_lstm,   dim3(256),      dim3(512), 0, stream, gx, Wq, Hx, hT);
  hipLaunchKernelGGL(k6_head,   dim3(B_),       dim3(64),  0, stream, hT, Wfc, bfc, out);
}

// Round 4
// 1140.186 us; speedup vs baseline: 4.1901x; 1.2342x over previous
//
#include <hip/hip_runtime.h>
#include <hip/hip_fp16.h>

// Problem constants
#define B_   64
#define T_   512
#define I_   128
#define H_   256
#define G4_  1024   // 4*H
#define R_   20
#define DA_  50
#define C_   10

typedef _Float16 half2_t __attribute__((ext_vector_type(2)));
typedef _Float16 half8_t __attribute__((ext_vector_type(8)));

__device__ __forceinline__ float fsigmoid(float x) {
  return __fdividef(1.0f, 1.0f + __expf(-x));
}
__device__ __forceinline__ float ftanh(float x) {
  return 1.0f - __fdividef(2.0f, __expf(2.0f * x) + 1.0f);
}

// ---------------------------------------------------------------------------
// K0: pack W_hh [256][1024] fp32 -> Wq[g][k2] half2 (column-major per gate col)
// ---------------------------------------------------------------------------
__global__ __launch_bounds__(256) void k0_pack(const float* __restrict__ Whh,
                                               half2_t* __restrict__ Wq) {
  int idx = blockIdx.x * 256 + threadIdx.x;   // 0..131071
  int g = idx & 1023, k2 = idx >> 10;
  half2_t h;
  h.x = (_Float16)Whh[(2 * k2) * G4_ + g];
  h.y = (_Float16)Whh[(2 * k2 + 1) * G4_ + g];
  Wq[g * 128 + k2] = h;
}

// ---------------------------------------------------------------------------
// K_init: zero the h-exchange mailboxes
// ---------------------------------------------------------------------------
__global__ __launch_bounds__(256) void k_init(unsigned long long* __restrict__ Hx) {
  int i = blockIdx.x * 256 + threadIdx.x;   // 16384 slots
  Hx[i] = 0ull;
}

// ---------------------------------------------------------------------------
// K1: S = (tanh(x@W1^T + b1))@W2^T + b2, layout S[B,R,T].
// 512 blocks x 256 threads; block = 64 rows. x tile + W1^T + A1 in LDS.
// ---------------------------------------------------------------------------
__global__ __launch_bounds__(256) void k1_scores(const float* __restrict__ x,
                                                 const float* __restrict__ W1,
                                                 const float* __restrict__ b1,
                                                 const float* __restrict__ W2,
                                                 const float* __restrict__ b2,
                                                 float* __restrict__ S) {
  __shared__ float xs[64][129];    // pad 129: 2-way (free) on row-indexed reads
  __shared__ float w1s[128][64];   // [k][d], cols 50..63 unused
  __shared__ float a1s[64][53];    // pad 53: 2-way on row-indexed reads
  int blk = blockIdx.x;
  int tid = threadIdx.x;
  int row0 = blk * 64;
  // load x tile (coalesced float4), scatter to padded LDS
  const float4* xv = (const float4*)(x + (size_t)row0 * I_);
#pragma unroll
  for (int ch = 0; ch < 8; ch++) {
    int fidx = ch * 256 + tid;          // 0..2047
    int r = fidx >> 5, k4 = (fidx & 31) << 2;
    float4 f = xv[fidx];
    xs[r][k4] = f.x; xs[r][k4 + 1] = f.y; xs[r][k4 + 2] = f.z; xs[r][k4 + 3] = f.w;
  }
  // load W1 [50][128] transposed into w1s[k][d]
  const float4* w1v = (const float4*)W1;
#pragma unroll
  for (int ch = 0; ch < 7; ch++) {
    int fidx = ch * 256 + tid;          // 0..1599
    if (fidx < 1600) {
      int d = fidx >> 5, k4 = (fidx & 31) << 2;
      float4 f = w1v[fidx];
      w1s[k4][d] = f.x; w1s[k4 + 1][d] = f.y; w1s[k4 + 2][d] = f.z; w1s[k4 + 3][d] = f.w;
    }
  }
  __syncthreads();
  // Phase B: A1 = tanh(x @ W1^T + b1); 4x4 register tile per thread
  int ty = tid >> 4, tx = tid & 15;
  float acc[4][4] = {};
#pragma unroll 4
  for (int k = 0; k < I_; k++) {
    float a0 = xs[4 * ty][k], a1 = xs[4 * ty + 1][k];
    float a2 = xs[4 * ty + 2][k], a3 = xs[4 * ty + 3][k];
    float4 bq = *(const float4*)&w1s[k][tx << 2];
    acc[0][0] += a0 * bq.x; acc[0][1] += a0 * bq.y; acc[0][2] += a0 * bq.z; acc[0][3] += a0 * bq.w;
    acc[1][0] += a1 * bq.x; acc[1][1] += a1 * bq.y; acc[1][2] += a1 * bq.z; acc[1][3] += a1 * bq.w;
    acc[2][0] += a2 * bq.x; acc[2][1] += a2 * bq.y; acc[2][2] += a2 * bq.z; acc[2][3] += a2 * bq.w;
    acc[3][0] += a3 * bq.x; acc[3][1] += a3 * bq.y; acc[3][2] += a3 * bq.z; acc[3][3] += a3 * bq.w;
  }
#pragma unroll
  for (int i = 0; i < 4; i++) {
#pragma unroll
    for (int j = 0; j < 4; j++) {
      int col = (tx << 2) + j;
      if (col < DA_) a1s[4 * ty + i][col] = tanhf(acc[i][j] + b1[col]);
    }
  }
  __syncthreads();
  // Phase C: S = A1 @ W2^T + b2
  int row = tid & 63, rq = tid >> 6;
  int bt = row0 + row;
  int b = bt >> 9, t = bt & 511;
#pragma unroll
  for (int m = 0; m < 5; m++) {
    int r = rq + (m << 2);
    float acc2 = b2[r];
#pragma unroll 10
    for (int d = 0; d < DA_; d++) acc2 += a1s[row][d] * W2[r * DA_ + d];
    S[((size_t)(b * R_ + r)) * T_ + t] = acc2;
  }
}

// ---------------------------------------------------------------------------
// K2: per (b,r): m = max_t S; E = exp(S-m); invd[t] = 1/cumsum(E)[t]
// ---------------------------------------------------------------------------
__global__ __launch_bounds__(64) void k2_prefix(const float* __restrict__ S,
                                                float* __restrict__ E,
                                                float* __restrict__ invd) {
  int br = blockIdx.x;            // b*20 + r
  int l = threadIdx.x;
  const float* Sr = S + (size_t)br * T_;
  float v[8];
  float m = -1e30f;
#pragma unroll
  for (int c = 0; c < 8; c++) {
    v[c] = Sr[c * 64 + l];
    m = fmaxf(m, v[c]);
  }
#pragma unroll
  for (int off = 32; off; off >>= 1) m = fmaxf(m, __shfl_xor(m, off));
  float carry = 0.f;
  for (int c = 0; c < 8; c++) {
    float e = expf(v[c] - m);
    float s = e;
#pragma unroll
    for (int off = 1; off < 64; off <<= 1) {
      float u = __shfl_up(s, off);
      if (l >= off) s += u;
    }
    E[(size_t)br * T_ + c * 64 + l] = e;
    invd[(size_t)br * T_ + c * 64 + l] = 1.f / (carry + s);
    carry += __shfl(s, 63);
  }
}

// ---------------------------------------------------------------------------
// K3a: per (b, chunk): P[b][c][r][i] = sum_{t in chunk} E[b,r,t] * x[b,t,i]
// ---------------------------------------------------------------------------
__global__ __launch_bounds__(128) void k3a(const float* __restrict__ x,
                                           const float* __restrict__ E,
                                           float* __restrict__ P) {
  int b = blockIdx.x >> 3, c = blockIdx.x & 7;
  int i = threadIdx.x;
  int t0 = c * 64;
  __shared__ float es[2][R_];
  float acc[R_];
#pragma unroll
  for (int r = 0; r < R_; r++) acc[r] = 0.f;
  float rE = 0.f;
  if (i < R_) rE = E[((size_t)(b * R_ + i)) * T_ + t0];
  const float* xb = x + (size_t)b * T_ * I_;
  float xv = xb[(size_t)t0 * I_ + i];
  int buf = 0;
  for (int tt = 0; tt < 64; tt++) {
    if (i < R_) es[buf][i] = rE;
    __syncthreads();
    if (tt + 1 < 64) {
      if (i < R_) rE = E[((size_t)(b * R_ + i)) * T_ + t0 + tt + 1];
    }
    float xcur = xv;
    if (tt + 1 < 64) xv = xb[(size_t)(t0 + tt + 1) * I_ + i];
#pragma unroll
    for (int r = 0; r < R_; r++) acc[r] += es[buf][r] * xcur;
    buf ^= 1;
  }
#pragma unroll
  for (int r = 0; r < R_; r++)
    P[(size_t)((b * 8 + c) * R_ + r) * I_ + i] = acc[r];
}

// ---------------------------------------------------------------------------
// K3b: exclusive prefix of P over chunks, per (b,r,i). In place.
// ---------------------------------------------------------------------------
__global__ __launch_bounds__(256) void k3b(float* __restrict__ P) {
  int gid = blockIdx.x * 256 + threadIdx.x;   // 0..163839
  int i = gid & 127;
  int r = (gid >> 7) % R_;
  int b = gid / (R_ * I_);
  float s = 0.f;
#pragma unroll
  for (int c = 0; c < 8; c++) {
    size_t idx = (size_t)((b * 8 + c) * R_ + r) * I_ + i;
    float v = P[idx];
    P[idx] = s;
    s += v;
  }
}

// ---------------------------------------------------------------------------
// K3c: per (b, chunk): acc init from P prefix, then 64 steps producing M.
// ---------------------------------------------------------------------------
__global__ __launch_bounds__(128) void k3c(const float* __restrict__ x,
                                           const float* __restrict__ E,
                                           const float* __restrict__ invd,
                                           const float* __restrict__ P,
                                           float* __restrict__ M) {
  int b = blockIdx.x >> 3, c = blockIdx.x & 7;
  int i = threadIdx.x;
  int t0 = c * 64;
  __shared__ float es[2][R_], ds[2][R_];
  float acc[R_];
#pragma unroll
  for (int r = 0; r < R_; r++)
    acc[r] = P[(size_t)((b * 8 + c) * R_ + r) * I_ + i];
  float rE = 0.f, rD = 0.f;
  if (i < R_)
    rE = E[((size_t)(b * R_ + i)) * T_ + t0];
  else if (i < 2 * R_)
    rD = invd[((size_t)(b * R_ + (i - R_))) * T_ + t0];
  const float* xb = x + (size_t)b * T_ * I_;
  float xv = xb[(size_t)t0 * I_ + i];
  int buf = 0;
  for (int tt = 0; tt < 64; tt++) {
    if (i < R_) es[buf][i] = rE;
    else if (i < 2 * R_) ds[buf][i - R_] = rD;
    __syncthreads();
    if (tt + 1 < 64) {
      if (i < R_)
        rE = E[((size_t)(b * R_ + i)) * T_ + t0 + tt + 1];
      else if (i < 2 * R_)
        rD = invd[((size_t)(b * R_ + (i - R_))) * T_ + t0 + tt + 1];
    }
    float xcur = xv;
    if (tt + 1 < 64) xv = xb[(size_t)(t0 + tt + 1) * I_ + i];
    float s = 0.f;
#pragma unroll
    for (int r = 0; r < R_; r++) {
      acc[r] += es[buf][r] * xcur;
      s += acc[r] * ds[buf][r];
    }
    M[(size_t)b * T_ * I_ + (size_t)(t0 + tt) * I_ + i] = s * (1.0f / R_);
    buf ^= 1;
  }
}

// ---------------------------------------------------------------------------
// K4: gx[row][g] = M[row,:] @ W_ih[:,g] + b[g].  Output fp16.
// ---------------------------------------------------------------------------
__global__ __launch_bounds__(256) void k4_gemm(const float* __restrict__ Mm,
                                               const float* __restrict__ Wih,
                                               const float* __restrict__ bg,
                                               __half* __restrict__ gx) {
  __shared__ float As[I_][64];   // [k][row]
  __shared__ float Bs[I_][64];   // [k][col]
  int row0 = blockIdx.x * 64, col0 = blockIdx.y * 64;
  int tid = threadIdx.x;
#pragma unroll
  for (int ch = 0; ch < 8; ch++) {
    int fidx = ch * 256 + tid;
    int r = fidx >> 5;
    int kk = (fidx & 31) << 2;
    float4 f = ((const float4*)(Mm + (size_t)(row0 + r) * I_))[fidx & 31];
    As[kk + 0][r] = f.x;
    As[kk + 1][r] = f.y;
    As[kk + 2][r] = f.z;
    As[kk + 3][r] = f.w;
  }
#pragma unroll
  for (int ch = 0; ch < 8; ch++) {
    int fidx = ch * 256 + tid;
    int k = fidx >> 4;
    int c4 = (fidx & 15) << 2;
    float4 f = *((const float4*)(Wih + (size_t)k * G4_ + col0 + c4));
    *((float4*)&Bs[k][c4]) = f;
  }
  __syncthreads();
  int ty = tid >> 4, tx = tid & 15;
  float acc[4][4] = {};
#pragma unroll 4
  for (int k = 0; k < I_; k++) {
    float4 a = *((float4*)&As[k][ty << 2]);
    float4 bq = *((float4*)&Bs[k][tx << 2]);
    acc[0][0] += a.x * bq.x; acc[0][1] += a.x * bq.y; acc[0][2] += a.x * bq.z; acc[0][3] += a.x * bq.w;
    acc[1][0] += a.y * bq.x; acc[1][1] += a.y * bq.y; acc[1][2] += a.y * bq.z; acc[1][3] += a.y * bq.w;
    acc[2][0] += a.z * bq.x; acc[2][1] += a.z * bq.y; acc[2][2] += a.z * bq.z; acc[2][3] += a.z * bq.w;
    acc[3][0] += a.w * bq.x; acc[3][1] += a.w * bq.y; acc[3][2] += a.w * bq.z; acc[3][3] += a.w * bq.w;
  }
#pragma unroll
  for (int ii = 0; ii < 4; ii++) {
#pragma unroll
    for (int jj = 0; jj < 4; jj++) {
      int row = row0 + (ty << 2) + ii;
      int col = col0 + (tx << 2) + jj;
      gx[(size_t)row * G4_ + col] = __float2half(acc[ii][jj] + bg[col]);
    }
  }
}

// ---------------------------------------------------------------------------
// K5: LSTM scan. 4 blocks per b; W_hh pinned in VGPRs via asm constraints.
// Thread map: lane = uw*8 + gate*2 + kh (uw = unit-in-wave 0..7).
// Wave owns all 4 gates of its 8 units -> gate gather + cell update are
// wave-local shuffles; ONE __syncthreads per step; hs double-buffered.
// Mailbox: {2 x fp16 | step tag} single 8B relaxed agent atomics (fence-free).
// ---------------------------------------------------------------------------
union WREG {
  unsigned u[64];
  half2_t h[64];
  uint4 q[16];
};

__global__ __launch_bounds__(512, 2) void k5_lstm(
    const __half* __restrict__ gx, const half2_t* __restrict__ Wq,
    unsigned long long* __restrict__ Hx, float* __restrict__ hT) {
  int b = blockIdx.x & 63;
  int p = blockIdx.x >> 6;
  int tid = threadIdx.x;
  int wave = tid >> 6;
  int lane = tid & 63;
  int kh = lane & 1;
  int gate = (lane >> 1) & 3;
  int uw = lane >> 3;                    // unit within wave (0..7)
  int u = wave * 8 + uw;                 // unit within partition (0..63)
  int gcol = gate * H_ + p * 64 + u;     // gate column (0..1023)

  __shared__ __align__(16) unsigned hsU[2][128];   // h double-buffer (fp16 x2)

  // Poller role: tid<96 polls remote partition q_, slot d_.
  int qi = tid >> 5;
  int q_ = qi + (qi >= p ? 1 : 0);
  int d_ = tid & 31;

  // Load W slice (64 half2 = 64 VGPRs) and PIN in registers.
  WREG w;
  {
    const uint4* wp = (const uint4*)(Wq + (size_t)gcol * 128 + kh * 64);
#pragma unroll
    for (int i = 0; i < 16; i++) w.q[i] = wp[i];
  }
#pragma unroll
  for (int j = 0; j < 64; j++) asm volatile("" : "+v"(w.u[j]));

  float cstate = 1.0f;                   // valid on leader lanes (lane&7)==0
  const __half* gxb = gx + (size_t)b * T_ * G4_;

  for (int t = 0; t < T_; t++) {
    // prefetch gate-input (even lanes only); overlaps poll latency
    float gxv = 0.f;
    if (!kh) gxv = (float)gxb[(size_t)t * G4_ + gcol];

    // stage h(t) into hs[t&1]
    if (t == 0) {
      if (tid < 128) hsU[0][tid] = 0x3C003C00u;    // h0 = 1.0 (fp16 pair)
    } else if (tid < 96) {
      const unsigned long long* src =
          Hx + ((size_t)(t & 1) * 64 + b) * 128 + q_ * 32 + d_;
      unsigned long long v;
      do {
        v = __hip_atomic_load(src, __ATOMIC_RELAXED, __HIP_MEMORY_SCOPE_AGENT);
      } while ((unsigned)(v >> 32) != (unsigned)t);
      hsU[t & 1][q_ * 32 + d_] = (unsigned)v;
    }
    __syncthreads();

    // partial dot over k-half kh (broadcast LDS reads, W in VGPRs)
    const half2_t* hb = (const half2_t*)hsU[t & 1] + kh * 64;
    float a0 = 0.f, a1 = 0.f, a2 = 0.f, a3 = 0.f;
#pragma unroll
    for (int i = 0; i < 16; i++) {
      half8_t hv = *(const half8_t*)(hb + i * 4);
      half2_t h0 = ((half2_t*)&hv)[0], h1 = ((half2_t*)&hv)[1];
      half2_t h2 = ((half2_t*)&hv)[2], h3 = ((half2_t*)&hv)[3];
      a0 = __builtin_amdgcn_fdot2(w.h[4 * i + 0], h0, a0, false);
      a1 = __builtin_amdgcn_fdot2(w.h[4 * i + 1], h1, a1, false);
      a2 = __builtin_amdgcn_fdot2(w.h[4 * i + 2], h2, a2, false);
      a3 = __builtin_amdgcn_fdot2(w.h[4 * i + 3], h3, a3, false);
    }
    float s = (a0 + a1) + (a2 + a3);
    s += __shfl_xor(s, 1);               // combine k-halves
    s += gxv;                            // even lanes: full gate preact

    // gather gates to leader (lane&7==0): f at +2, g at +4, o at +6
    float f1 = __shfl_down(s, 2);
    float f2 = __shfl_down(s, 4);
    float f3 = __shfl_down(s, 6);
    unsigned hu = 0;
    if ((lane & 7) == 0) {
      float vi = fsigmoid(s);
      float vf = fsigmoid(f1);
      float vg = ftanh(f2);
      float vo = fsigmoid(f3);
      cstate = vf * cstate + vi * vg;
      float h = vo * ftanh(cstate);
      hu = (unsigned)__half_as_ushort(__float2half(h));
      if (t == T_ - 1) hT[b * H_ + p * 64 + u] = h;
    }
    unsigned hup = (unsigned)__shfl_down((int)hu, 8);
    if ((lane & 15) == 0 && (t + 1) < T_) {
      unsigned h2pack = hu | (hup << 16);
      int slot = p * 32 + wave * 4 + (lane >> 4);
      unsigned long long pkt =
          (unsigned long long)h2pack |
          ((unsigned long long)(unsigned)(t + 1) << 32);
      unsigned long long* dst =
          Hx + ((size_t)((t + 1) & 1) * 64 + b) * 128 + slot;
      __hip_atomic_store(dst, pkt, __ATOMIC_RELAXED, __HIP_MEMORY_SCOPE_AGENT);
      hsU[(t + 1) & 1][slot] = h2pack;   // local copy for next step
    }
    // no second barrier: next-step writes target the other hs buffer, and
    // the next step's __syncthreads orders them before all reads.
  }
}

// ---------------------------------------------------------------------------
// K6: logits = hT @ Wfc^T + bfc; softmax.  One wave per b.
// ---------------------------------------------------------------------------
__global__ __launch_bounds__(64) void k6_head(const float* __restrict__ hT,
                                              const float* __restrict__ Wfc,
                                              const float* __restrict__ bfc,
                                              float* __restrict__ out) {
  int b = blockIdx.x, l = threadIdx.x;
  const float* h = hT + b * H_;
  float p[C_];
#pragma unroll
  for (int c = 0; c < C_; c++) p[c] = 0.f;
#pragma unroll
  for (int q = 0; q < 4; q++) {
    float hv = h[q * 64 + l];
#pragma unroll
    for (int c = 0; c < C_; c++) p[c] += hv * Wfc[c * H_ + q * 64 + l];
  }
#pragma unroll
  for (int c = 0; c < C_; c++)
    for (int off = 32; off; off >>= 1) p[c] += __shfl_xor(p[c], off);
  if (l == 0) {
    float m = -1e30f, e[C_], sum = 0.f;
    for (int c = 0; c < C_; c++) { p[c] += bfc[c]; m = fmaxf(m, p[c]); }
    for (int c = 0; c < C_; c++) { e[c] = expf(p[c] - m); sum += e[c]; }
    for (int c = 0; c < C_; c++) out[b * C_ + c] = e[c] / sum;
  }
}

// ---------------------------------------------------------------------------
// Workspace layout (float offsets):
//   Hx    [2][64][128] u64 = dwords [0, 32768)   (aliases S; S dead after k2)
//   S     [B,R,T]        wsf + 0
//   E     [B,R,T]        wsf + 655360
//   INVD  [B,R,T]        wsf + 1310720
//   M     [B,T,I]        wsf + 1966080
//   hT    [B,H]          wsf + 6160384
//   Wq    [1024][128]h2  wsf + 6176768  (131072 dwords)
//   gx    [B,T,4H] fp16  wsf + 6307840  (16777216 dwords)
//   P     [B][8][R][I]   aliases gx region (P dead before k4 writes gx)
// ---------------------------------------------------------------------------
extern "C" void kernel_launch(void* const* d_in, const int* in_sizes, int n_in,
                              void* d_out, int out_size, void* d_ws, size_t ws_size,
                              hipStream_t stream) {
  const float* x   = (const float*)d_in[0];
  const float* Wih = (const float*)d_in[1];
  const float* Whh = (const float*)d_in[2];
  const float* bg  = (const float*)d_in[3];
  const float* W1  = (const float*)d_in[4];
  const float* b1  = (const float*)d_in[5];
  const float* W2  = (const float*)d_in[6];
  const float* b2  = (const float*)d_in[7];
  const float* Wfc = (const float*)d_in[8];
  const float* bfc = (const float*)d_in[9];
  float* out = (float*)d_out;

  float* wsf = (float*)d_ws;
  unsigned long long* Hx = (unsigned long long*)wsf;
  float* S    = wsf;
  float* E    = wsf + 655360;
  float* INVD = wsf + 1310720;
  float* Mm   = wsf + 1966080;
  float* hT   = wsf + 6160384;
  half2_t* Wq = (half2_t*)(wsf + 6176768);
  __half* gx  = (__half*)(wsf + 6307840);
  float* P    = wsf + 6307840;           // aliases gx region (disjoint in time)

  hipLaunchKernelGGL(k0_pack,   dim3(512),     dim3(256), 0, stream, Whh, Wq);
  hipLaunchKernelGGL(k1_scores, dim3(512),     dim3(256), 0, stream, x, W1, b1, W2, b2, S);
  hipLaunchKernelGGL(k2_prefix, dim3(B_ * R_), dim3(64),  0, stream, S, E, INVD);
  hipLaunchKernelGGL(k3a,       dim3(512),     dim3(128), 0, stream, x, E, P);
  hipLaunchKernelGGL(k3b,       dim3(640),     dim3(256), 0, stream, P);
  hipLaunchKernelGGL(k3c,       dim3(512),     dim3(128), 0, stream, x, E, INVD, P, Mm);
  hipLaunchKernelGGL(k4_gemm,   dim3(512, 16), dim3(256), 0, stream, Mm, Wih, bg, gx);
  hipLaunchKernelGGL(k_init,    dim3(64),      dim3(256), 0, stream, Hx);
  hipLaunchKernelGGL(k5_lstm,   dim3(256),     dim3(512), 0, stream, gx, Wq, Hx, hT);
  hipLaunchKernelGGL(k6_head,   dim3(B_),      dim3(64),  0, stream, hT, Wfc, bfc, out);
}